// Round 10
// baseline (862.359 us; speedup 1.0000x reference)
//
#include <hip/hip_runtime.h>
#include <hip/hip_fp16.h>
#include <hip/hip_cooperative_groups.h>
#include <math.h>

// N=50000 nodes, E=800000 edges, D=64, H=2 heads, C=64 per-head, H*C=128
// GEMM output cols concatenated: [Q:128 | K:128 | V:128 | skip:64] = 448

typedef _Float16 half8 __attribute__((ext_vector_type(8)));
typedef _Float16 half4 __attribute__((ext_vector_type(4)));
typedef float floatx4 __attribute__((ext_vector_type(4)));

struct __align__(16) H8 { __half2 a, b, c, d; };   // 8 f16 = 16 B
struct __align__(16) F16x8 { _Float16 v[8]; };     // 16 B

static __device__ inline __half2 shfl_xor_h2(__half2 v, int off) {
    union { __half2 h; int i; } u;
    u.h = v;
    u.i = __shfl_xor(u.i, off);
    return u.h;
}

// ---------------------------------------------------------------------------
// Shared GEMM tile body (operand-swapped MFMA):
// [rows,64] @ WhT^T -> Q f16 [N,128], KV f16 [N,256], skip f32 [N,64]
// 1 wave = 16 rows, 28 col-tiles; lane owns 4 consecutive out-cols of 1 row.
// ---------------------------------------------------------------------------
template <int F32IN>
static __device__ __forceinline__ void gemm_tile_body(
    const void* __restrict__ Xin, int rows,
    const _Float16* __restrict__ WhT, const float* __restrict__ Ball,
    _Float16* __restrict__ Qo, _Float16* __restrict__ KVo,
    float* __restrict__ So, int blk, int tix) {
    const int lane = tix & 63;
    const int w    = tix >> 6;
    const int kg   = lane >> 4;
    const int li   = lane & 15;
    const int rbase = blk * 64 + w * 16;
    const int row  = rbase + li;
    const int crow = row < rows ? row : rows - 1;

    half8 a0, a1;
    if constexpr (F32IN) {
        const float* xp = (const float*)Xin + (size_t)crow * 64 + kg * 8;
        float4 f0 = *(const float4*)xp;
        float4 f1 = *(const float4*)(xp + 4);
        float4 f2 = *(const float4*)(xp + 32);
        float4 f3 = *(const float4*)(xp + 36);
        a0 = half8{(_Float16)f0.x, (_Float16)f0.y, (_Float16)f0.z, (_Float16)f0.w,
                   (_Float16)f1.x, (_Float16)f1.y, (_Float16)f1.z, (_Float16)f1.w};
        a1 = half8{(_Float16)f2.x, (_Float16)f2.y, (_Float16)f2.z, (_Float16)f2.w,
                   (_Float16)f3.x, (_Float16)f3.y, (_Float16)f3.z, (_Float16)f3.w};
    } else {
        const _Float16* xp = (const _Float16*)Xin + (size_t)crow * 64 + kg * 8;
        a0 = *(const half8*)xp;
        a1 = *(const half8*)(xp + 32);
    }

#pragma unroll
    for (int t = 0; t < 28; ++t) {
        const _Float16* wp = WhT + (size_t)(t * 16 + li) * 64 + kg * 8;
        half8 b0 = *(const half8*)wp;
        half8 b1 = *(const half8*)(wp + 32);
        floatx4 acc = {0.f, 0.f, 0.f, 0.f};
        acc = __builtin_amdgcn_mfma_f32_16x16x32_f16(b0, a0, acc, 0, 0, 0);
        acc = __builtin_amdgcn_mfma_f32_16x16x32_f16(b1, a1, acc, 0, 0, 0);
        const int c0 = t * 16 + kg * 4;
        float4 bias = *(const float4*)(Ball + c0);
        if (row < rows) {
            float o0 = acc[0] + bias.x, o1 = acc[1] + bias.y;
            float o2 = acc[2] + bias.z, o3 = acc[3] + bias.w;
            if (t < 8) {
                *(half4*)(Qo + (size_t)row * 128 + c0) =
                    half4{(_Float16)o0, (_Float16)o1, (_Float16)o2, (_Float16)o3};
            } else if (t < 24) {
                *(half4*)(KVo + (size_t)row * 256 + (c0 - 128)) =
                    half4{(_Float16)o0, (_Float16)o1, (_Float16)o2, (_Float16)o3};
            } else {
                *(float4*)(So + (size_t)row * 64 + (c0 - 384)) =
                    make_float4(o0, o1, o2, o3);
            }
        }
    }
}

// ---------------------------------------------------------------------------
// Weight-prep device body (both layers) + zero counts
// ---------------------------------------------------------------------------
static __device__ __forceinline__ void prep_body(
    const float* const* W, _Float16* wht1, _Float16* wht2,
    float* ball1, float* ball2, int* counts, int n, int tid, int nt) {
    for (int idx = tid; idx < 448 * 64; idx += nt) {
        int c = idx >> 6, k = idx & 63;
        float v1, v2;
        if (c < 128)      { v1 = W[0][k*128 + c];        v2 = W[8][k*128 + c]; }
        else if (c < 256) { v1 = W[2][k*128 + (c-128)];  v2 = W[10][k*128 + (c-128)]; }
        else if (c < 384) { v1 = W[4][k*128 + (c-256)];  v2 = W[12][k*128 + (c-256)]; }
        else              { v1 = W[6][k*64 + (c-384)];   v2 = W[14][k*64 + (c-384)]; }
        wht1[c*64 + k] = (_Float16)v1;
        wht2[c*64 + k] = (_Float16)v2;
        if (k == 0) {
            float b1, b2;
            if (c < 128)      { b1 = W[1][c];       b2 = W[9][c]; }
            else if (c < 256) { b1 = W[3][c-128];   b2 = W[11][c-128]; }
            else if (c < 384) { b1 = W[5][c-256];   b2 = W[13][c-256]; }
            else              { b1 = W[7][c-384];   b2 = W[15][c-384]; }
            ball1[c] = b1;
            ball2[c] = b2;
        }
    }
    for (int i = tid; i < n; i += nt) counts[i] = 0;
}

// ---------------------------------------------------------------------------
// Cooperative setup kernel. __launch_bounds__(256, 4): guaranteed 4 blocks/CU
// => grid of 1024 blocks (4 x 256 CUs) is always co-resident (guide §1).
// ph0 {prep + zero} -> ph1 {GEMM layer1 + hist} -> ph2 partial -> ph3 scan
// -> ph4 final -> ph5 scatter
// ---------------------------------------------------------------------------
struct SetupArgs {
    const float* W[16];
    const float* x;          // [N][64] f32
    const int* ei;           // [2][E]
    int* counts;
    int* offsets;            // [N+1]
    int* cursor;
    int* ssrc;               // [E]
    int* partials;           // [256]
    int* blockbase;          // [256]
    _Float16* wht1;          // [448][64]
    _Float16* wht2;
    float* ball1;            // [448]
    float* ball2;
    _Float16* qh;            // [N][128]
    _Float16* kv;            // [N][256]
    float* sk1;              // [N][64]
    int N, E;
};

__global__ __launch_bounds__(256, 4) void setup_coop(SetupArgs a) {
    namespace cg = cooperative_groups;
    cg::grid_group grid = cg::this_grid();
    const int tid = blockIdx.x * 256 + threadIdx.x;
    const int nt  = gridDim.x * 256;
    __shared__ int sh[256];
    __shared__ int ws[4];

    // ---- phase 0 ----
    prep_body(a.W, a.wht1, a.wht2, a.ball1, a.ball2, a.counts, a.N, tid, nt);
    grid.sync();

    // ---- phase 1: GEMM layer 1 (independent of CSR) + histogram ----
    {
        const int ntile = (a.N + 63) >> 6;
        for (int tb = blockIdx.x; tb < ntile; tb += gridDim.x)
            gemm_tile_body<1>(a.x, a.N, a.wht1, a.ball1, a.qh, a.kv, a.sk1,
                              tb, threadIdx.x);
        const int* dst = a.ei + a.E;
        for (int i = tid; i < a.E; i += nt) atomicAdd(&a.counts[dst[i]], 1);
    }
    grid.sync();

    // ---- phase 2: per-chunk partial sums ----
    const int nch = (a.N + 255) >> 8;   // 196 <= 256
    for (int b = blockIdx.x; b < nch; b += gridDim.x) {
        int idx = b * 256 + threadIdx.x;
        int v = (idx < a.N) ? a.counts[idx] : 0;
        for (int off = 1; off < 64; off <<= 1) v += __shfl_xor(v, off);
        if ((threadIdx.x & 63) == 0) ws[threadIdx.x >> 6] = v;
        __syncthreads();
        if (threadIdx.x == 0)
            a.partials[b] = ws[0] + ws[1] + ws[2] + ws[3];
        __syncthreads();
    }
    grid.sync();

    // ---- phase 3: block 0 exclusive-scans the partials ----
    if (blockIdx.x == 0) {
        int t = threadIdx.x;
        int v = (t < nch) ? a.partials[t] : 0;
        sh[t] = v;
        __syncthreads();
        for (int off = 1; off < 256; off <<= 1) {
            int u = (t >= off) ? sh[t - off] : 0;
            __syncthreads();
            sh[t] += u;
            __syncthreads();
        }
        if (t < nch) a.blockbase[t] = sh[t] - v;
    }
    grid.sync();

    // ---- phase 4: per-chunk exclusive scan -> offsets, cursor ----
    for (int b = blockIdx.x; b < nch; b += gridDim.x) {
        int t = threadIdx.x;
        int idx = b * 256 + t;
        int v = (idx < a.N) ? a.counts[idx] : 0;
        sh[t] = v;
        __syncthreads();
        for (int off = 1; off < 256; off <<= 1) {
            int u = (t >= off) ? sh[t - off] : 0;
            __syncthreads();
            sh[t] += u;
            __syncthreads();
        }
        if (idx < a.N) {
            int ex = a.blockbase[b] + sh[t] - v;
            a.offsets[idx] = ex;
            a.cursor[idx]  = ex;
        }
        if (idx == 0) a.offsets[a.N] = a.E;
        __syncthreads();
    }
    grid.sync();

    // ---- phase 5: scatter src into dst-sorted order ----
    {
        const int* dst = a.ei + a.E;
        const int* srcp = a.ei;
        for (int i = tid; i < a.E; i += nt) {
            int pos = atomicAdd(&a.cursor[dst[i]], 1);
            a.ssrc[pos] = srcp[i];
        }
    }
}

// ---------------------------------------------------------------------------
// Fallback standalone kernels (r8 path, known-good)
// ---------------------------------------------------------------------------
__global__ __launch_bounds__(256) void prep_w_both(
    const float* __restrict__ W0, const float* __restrict__ B0,
    const float* __restrict__ W1, const float* __restrict__ B1,
    const float* __restrict__ W2, const float* __restrict__ B2,
    const float* __restrict__ W3, const float* __restrict__ B3,
    const float* __restrict__ W4, const float* __restrict__ B4,
    const float* __restrict__ W5, const float* __restrict__ B5,
    const float* __restrict__ W6, const float* __restrict__ B6,
    const float* __restrict__ W7, const float* __restrict__ B7,
    _Float16* __restrict__ wht1, _Float16* __restrict__ wht2,
    float* __restrict__ ball1, float* __restrict__ ball2,
    int* __restrict__ counts, int n) {
    const float* W[16] = {W0,B0,W1,B1,W2,B2,W3,B3,W4,B4,W5,B5,W6,B6,W7,B7};
    prep_body(W, wht1, wht2, ball1, ball2, counts, n,
              blockIdx.x * 256 + threadIdx.x, gridDim.x * 256);
}

__global__ __launch_bounds__(256) void hist_kernel(const int* __restrict__ dst,
                                                   int* __restrict__ counts, int e) {
    int i = blockIdx.x * 256 + threadIdx.x;
    if (i < e) atomicAdd(&counts[dst[i]], 1);
}

__global__ __launch_bounds__(256) void partial_kernel(const int* __restrict__ counts,
                                                      int* __restrict__ partials, int n) {
    int idx = blockIdx.x * 256 + threadIdx.x;
    int v = (idx < n) ? counts[idx] : 0;
    for (int off = 1; off < 64; off <<= 1) v += __shfl_xor(v, off);
    __shared__ int ws[4];
    int wid = threadIdx.x >> 6;
    if ((threadIdx.x & 63) == 0) ws[wid] = v;
    __syncthreads();
    if (threadIdx.x == 0) partials[blockIdx.x] = ws[0] + ws[1] + ws[2] + ws[3];
}

__global__ __launch_bounds__(256) void scanp_kernel(const int* __restrict__ partials,
                                                    int* __restrict__ blockbase, int nb) {
    __shared__ int s[256];
    int t = threadIdx.x;
    int v = (t < nb) ? partials[t] : 0;
    s[t] = v;
    __syncthreads();
    for (int off = 1; off < 256; off <<= 1) {
        int u = (t >= off) ? s[t - off] : 0;
        __syncthreads();
        s[t] += u;
        __syncthreads();
    }
    if (t < nb) blockbase[t] = s[t] - v;
}

__global__ __launch_bounds__(256) void final_kernel(const int* __restrict__ counts,
                                                    const int* __restrict__ blockbase,
                                                    int* __restrict__ offsets,
                                                    int* __restrict__ cursor,
                                                    int n, int total) {
    __shared__ int s[256];
    int t = threadIdx.x;
    int idx = blockIdx.x * 256 + t;
    int v = (idx < n) ? counts[idx] : 0;
    s[t] = v;
    __syncthreads();
    for (int off = 1; off < 256; off <<= 1) {
        int u = (t >= off) ? s[t - off] : 0;
        __syncthreads();
        s[t] += u;
        __syncthreads();
    }
    if (idx < n) {
        int ex = blockbase[blockIdx.x] + s[t] - v;
        offsets[idx] = ex;
        cursor[idx]  = ex;
    }
    if (idx == 0) offsets[n] = total;
}

__global__ __launch_bounds__(256) void scatter_kernel(const int* __restrict__ src,
                                                      const int* __restrict__ dst,
                                                      int* __restrict__ cursor,
                                                      int* __restrict__ ssrc, int e) {
    int i = blockIdx.x * 256 + threadIdx.x;
    if (i < e) {
        int pos = atomicAdd(&cursor[dst[i]], 1);
        ssrc[pos] = src[i];
    }
}

template <int F32IN>
__global__ __launch_bounds__(256) void gemm_mfma(
    const void* __restrict__ Xin, int rows,
    const _Float16* __restrict__ WhT, const float* __restrict__ Ball,
    _Float16* __restrict__ Qo, _Float16* __restrict__ KVo,
    float* __restrict__ So) {
    gemm_tile_body<F32IN>(Xin, rows, WhT, Ball, Qo, KVo, So,
                          blockIdx.x, threadIdx.x);
}

// ---------------------------------------------------------------------------
// Attention: 1 wave/node. lane = slot(2b) | head(1b) | li(3b): 8 ch/lane,
// 4 edge-slots, 2 edges/slot/iter (8 edges/iter). Software-pipelined.
// ---------------------------------------------------------------------------
template <int HALF_OUT>
__global__ __launch_bounds__(256) void attn_kernel(
    const _Float16* __restrict__ Qh,    // [N][128] f16
    const _Float16* __restrict__ KV,    // [N][256] f16
    const int* __restrict__ offs, const int* __restrict__ ssrc,
    const float* __restrict__ skip,     // [N][64] f32
    float* __restrict__ outF, _Float16* __restrict__ outH, int n) {
    int node = (blockIdx.x * 256 + threadIdx.x) >> 6;
    int lane = threadIdx.x & 63;
    if (node >= n) return;
    const int slot = lane >> 4;
    const int koff = ((lane >> 3) & 1) * 64 + (lane & 7) * 8;  // head*64 + li*8

    H8 q = *(const H8*)(Qh + (size_t)node * 128 + koff);

    const int beg = offs[node], end = offs[node + 1];
    float m = -INFINITY, l = 0.f;
    __half2 hz = __float2half2_rn(0.f);
    __half2 ha = hz, hb = hz, hc = hz, hd = hz;   // packed O accumulator (8 ch)

    int i = beg;
    bool b0 = false, b1 = false;
    H8 k0, k1, v0, v1;
    if (i < end) {
        int e0 = i + slot, e1 = i + 4 + slot;
        b0 = e0 < end; b1 = e1 < end;
        int s0 = ssrc[b0 ? e0 : end - 1];
        int s1 = ssrc[b1 ? e1 : end - 1];
        const _Float16* p0 = KV + (size_t)s0 * 256 + koff;
        const _Float16* p1 = KV + (size_t)s1 * 256 + koff;
        k0 = *(const H8*)p0; v0 = *(const H8*)(p0 + 128);
        k1 = *(const H8*)p1; v1 = *(const H8*)(p1 + 128);
    }

    while (i < end) {
        const int inext = i + 8;
        bool nb0 = false, nb1 = false;
        H8 nk0, nk1, nv0, nv1;
        if (inext < end) {   // prefetch next iteration (wave-uniform branch)
            int e0 = inext + slot, e1 = inext + 4 + slot;
            nb0 = e0 < end; nb1 = e1 < end;
            int s0 = ssrc[nb0 ? e0 : end - 1];
            int s1 = ssrc[nb1 ? e1 : end - 1];
            const _Float16* p0 = KV + (size_t)s0 * 256 + koff;
            const _Float16* p1 = KV + (size_t)s1 * 256 + koff;
            nk0 = *(const H8*)p0; nv0 = *(const H8*)(p0 + 128);
            nk1 = *(const H8*)p1; nv1 = *(const H8*)(p1 + 128);
        }

        __half2 dh0 = __hfma2(q.a, k0.a, __hfma2(q.b, k0.b, __hfma2(q.c, k0.c, __hmul2(q.d, k0.d))));
        __half2 dh1 = __hfma2(q.a, k1.a, __hfma2(q.b, k1.b, __hfma2(q.c, k1.c, __hmul2(q.d, k1.d))));
        __half2 pd = __halves2half2(__hadd(dh0.x, dh0.y), __hadd(dh1.x, dh1.y));
        pd = __hadd2(pd, shfl_xor_h2(pd, 1));
        pd = __hadd2(pd, shfl_xor_h2(pd, 2));
        pd = __hadd2(pd, shfl_xor_h2(pd, 4));
        float d0 = b0 ? __half2float(pd.x) * 0.125f : -INFINITY;
        float d1 = b1 ? __half2float(pd.y) * 0.125f : -INFINITY;

        float mx = fmaxf(fmaxf(d0, d1), m);
        float sc = (m == -INFINITY) ? 0.f : __expf(m - mx);
        float p0e = b0 ? __expf(d0 - mx) : 0.f;
        float p1e = b1 ? __expf(d1 - mx) : 0.f;
        l = fmaf(l, sc, p0e + p1e);

        __half2 hsc = __float2half2_rn(sc);
        __half2 hp0 = __float2half2_rn(p0e);
        __half2 hp1 = __float2half2_rn(p1e);
        ha = __hfma2(hp0, v0.a, __hfma2(hp1, v1.a, __hmul2(ha, hsc)));
        hb = __hfma2(hp0, v0.b, __hfma2(hp1, v1.b, __hmul2(hb, hsc)));
        hc = __hfma2(hp0, v0.c, __hfma2(hp1, v1.c, __hmul2(hc, hsc)));
        hd = __hfma2(hp0, v0.d, __hfma2(hp1, v1.d, __hmul2(hd, hsc)));
        m = mx;

        i = inext;
        b0 = nb0; b1 = nb1;
        k0 = nk0; k1 = nk1; v0 = nv0; v1 = nv1;
    }

    // unpack accumulator to f32 for the slot merges
    float acc[8];
    {
        float2 t0 = __half22float2(ha), t1 = __half22float2(hb);
        float2 t2 = __half22float2(hc), t3 = __half22float2(hd);
        acc[0] = t0.x; acc[1] = t0.y; acc[2] = t1.x; acc[3] = t1.y;
        acc[4] = t2.x; acc[5] = t2.y; acc[6] = t3.x; acc[7] = t3.y;
    }

    // merge the 4 slot states (xor 16, xor 32)
#pragma unroll
    for (int off = 16; off <= 32; off <<= 1) {
        float mo = __shfl_xor(m, off);
        float lo = __shfl_xor(l, off);
        float ao[8];
#pragma unroll
        for (int j = 0; j < 8; ++j) ao[j] = __shfl_xor(acc[j], off);
        float mm = fmaxf(m, mo);
        float sa = (m  == -INFINITY) ? 0.f : __expf(m  - mm);
        float sb = (mo == -INFINITY) ? 0.f : __expf(mo - mm);
        l = l * sa + lo * sb;
#pragma unroll
        for (int j = 0; j < 8; ++j) acc[j] = acc[j] * sa + ao[j] * sb;
        m = mm;
    }
    // per-head normalize, then head mean (xor 8)
    float inv = 1.f / (l + 1e-16f);
    float r[8];
#pragma unroll
    for (int j = 0; j < 8; ++j) r[j] = acc[j] * inv;
#pragma unroll
    for (int j = 0; j < 8; ++j) r[j] = 0.5f * (r[j] + __shfl_xor(r[j], 8));

    if (lane < 8) {  // slot0, head0: lane owns ch lane*8..+7
        const float4* sp = (const float4*)(skip + (size_t)node * 64 + lane * 8);
        float4 s0 = sp[0], s1 = sp[1];
        float o[8] = {s0.x + r[0], s0.y + r[1], s0.z + r[2], s0.w + r[3],
                      s1.x + r[4], s1.y + r[5], s1.z + r[6], s1.w + r[7]};
        if (HALF_OUT) {
            F16x8 h;
#pragma unroll
            for (int j = 0; j < 8; ++j) h.v[j] = (_Float16)o[j];
            *(F16x8*)(outH + (size_t)node * 64 + lane * 8) = h;
        } else {
            float4* op = (float4*)(outF + (size_t)node * 64 + lane * 8);
            op[0] = make_float4(o[0], o[1], o[2], o[3]);
            op[1] = make_float4(o[4], o[5], o[6], o[7]);
        }
    }
}

// ---------------------------------------------------------------------------
// Host launch: coop path = 4 dispatches; fallback = 10 (r8-equivalent)
// ---------------------------------------------------------------------------
extern "C" void kernel_launch(void* const* d_in, const int* in_sizes, int n_in,
                              void* d_out, int out_size, void* d_ws, size_t ws_size,
                              hipStream_t stream) {
    const float* x  = (const float*)d_in[0];
    const int*   ei = (const int*)d_in[1];  // [2,E]: row0=src, row1=dst
    const int N = in_sizes[0] / 64;
    const int E = in_sizes[1] / 2;

    const float* w[16];
    for (int i = 0; i < 16; ++i) w[i] = (const float*)d_in[2 + i];

    char* base = (char*)d_ws;
    size_t off = 0;
    auto alloc = [&](size_t bytes) {
        void* p = base + off;
        off = (off + bytes + 255) & ~(size_t)255;
        return p;
    };
    _Float16* qh   = (_Float16*)alloc((size_t)N * 128 * 2);
    _Float16* kv   = (_Float16*)alloc((size_t)N * 256 * 2);
    float*    sk1  = (float*)alloc((size_t)N * 64 * 4);
    _Float16* h1h  = (_Float16*)alloc((size_t)N * 64 * 2);
    _Float16* wht1 = (_Float16*)alloc(448 * 64 * 2);
    _Float16* wht2 = (_Float16*)alloc(448 * 64 * 2);
    float*    ball1 = (float*)alloc(448 * 4);
    float*    ball2 = (float*)alloc(448 * 4);
    int* counts    = (int*)alloc((size_t)N * 4);
    int* offsets   = (int*)alloc((size_t)(N + 1) * 4);
    int* cursor    = (int*)alloc((size_t)N * 4);
    int* ssrc      = (int*)alloc((size_t)E * 4);
    int* partials  = (int*)alloc(1024 * 4);
    int* blockbase = (int*)alloc(1024 * 4);

    SetupArgs sa;
    for (int i = 0; i < 16; ++i) sa.W[i] = w[i];
    sa.x = x; sa.ei = ei;
    sa.counts = counts; sa.offsets = offsets; sa.cursor = cursor; sa.ssrc = ssrc;
    sa.partials = partials; sa.blockbase = blockbase;
    sa.wht1 = wht1; sa.wht2 = wht2; sa.ball1 = ball1; sa.ball2 = ball2;
    sa.qh = qh; sa.kv = kv; sa.sk1 = sk1;
    sa.N = N; sa.E = E;

    // __launch_bounds__(256,4) guarantees 4 blocks/CU co-residency, so a
    // 1024-block grid (4 x 256 CUs) always satisfies the cooperative-launch
    // capacity check (r9 failed at 2048 = at/over the limit).
    void* kargs[] = { &sa };
    hipError_t cerr = hipLaunchCooperativeKernel(
        (const void*)setup_coop, dim3(1024), dim3(256), kargs, 0, stream);

    const int gb = (N + 63) / 64;
    const int ab = (N * 64 + 255) / 256;

    if (cerr != hipSuccess) {
        // Fallback: separate-kernel path (r8, known-good)
        int eb = (E + 255) / 256;
        int nb = (N + 255) / 256;
        prep_w_both<<<224, 256, 0, stream>>>(
            w[0], w[1], w[2], w[3], w[4], w[5], w[6], w[7],
            w[8], w[9], w[10], w[11], w[12], w[13], w[14], w[15],
            wht1, wht2, ball1, ball2, counts, N);
        hist_kernel<<<eb, 256, 0, stream>>>(ei + E, counts, E);
        partial_kernel<<<nb, 256, 0, stream>>>(counts, partials, N);
        scanp_kernel<<<1, 256, 0, stream>>>(partials, blockbase, nb);
        final_kernel<<<nb, 256, 0, stream>>>(counts, blockbase, offsets, cursor, N, E);
        scatter_kernel<<<eb, 256, 0, stream>>>(ei, ei + E, cursor, ssrc, E);
        gemm_mfma<1><<<gb, 256, 0, stream>>>(x, N, wht1, ball1, qh, kv, sk1);
    }

    // --- layer 1 attention (gemm1 ran in setup_coop or fallback) ---
    attn_kernel<1><<<ab, 256, 0, stream>>>(qh, kv, offsets, ssrc, sk1,
                                           nullptr, h1h, N);
    // --- layer 2 ---
    gemm_mfma<0><<<gb, 256, 0, stream>>>(h1h, N, wht2, ball2, qh, kv, (float*)d_out);
    attn_kernel<0><<<ab, 256, 0, stream>>>(qh, kv, offsets, ssrc, (float*)d_out,
                                           (float*)d_out, nullptr, N);
}

// Round 11
// 315.620 us; speedup vs baseline: 2.7323x; 2.7323x over previous
//
#include <hip/hip_runtime.h>
#include <hip/hip_fp16.h>
#include <math.h>

// N=50000 nodes, E=800000 edges, D=64, H=2 heads, C=64 per-head, H*C=128
// GEMM output cols concatenated: [Q:128 | K:128 | V:128 | skip:64] = 448

typedef _Float16 half8 __attribute__((ext_vector_type(8)));
typedef _Float16 half4 __attribute__((ext_vector_type(4)));
typedef float floatx4 __attribute__((ext_vector_type(4)));

struct __align__(16) H8 { __half2 a, b, c, d; };   // 8 f16 = 16 B
struct __align__(16) F16x8 { _Float16 v[8]; };     // 16 B

static __device__ inline __half2 shfl_xor_h2(__half2 v, int off) {
    union { __half2 h; int i; } u;
    u.h = v;
    u.i = __shfl_xor(u.i, off);
    return u.h;
}

// ---------------------------------------------------------------------------
// Weight prep (both layers) + zero counts + zero scan state
// ---------------------------------------------------------------------------
__global__ __launch_bounds__(256) void prep_w_both(
    const float* __restrict__ W0, const float* __restrict__ B0,
    const float* __restrict__ W1, const float* __restrict__ B1,
    const float* __restrict__ W2, const float* __restrict__ B2,
    const float* __restrict__ W3, const float* __restrict__ B3,
    const float* __restrict__ W4, const float* __restrict__ B4,
    const float* __restrict__ W5, const float* __restrict__ B5,
    const float* __restrict__ W6, const float* __restrict__ B6,
    const float* __restrict__ W7, const float* __restrict__ B7,
    _Float16* __restrict__ wht1, _Float16* __restrict__ wht2,
    float* __restrict__ ball1, float* __restrict__ ball2,
    int* __restrict__ counts, unsigned long long* __restrict__ state, int n) {
    const int tid = blockIdx.x * 256 + threadIdx.x;
    const int nt  = gridDim.x * 256;
    for (int idx = tid; idx < 448 * 64; idx += nt) {
        int c = idx >> 6, k = idx & 63;
        float v1, v2;
        if (c < 128)      { v1 = W0[k*128 + c];       v2 = W4[k*128 + c]; }
        else if (c < 256) { v1 = W1[k*128 + (c-128)]; v2 = W5[k*128 + (c-128)]; }
        else if (c < 384) { v1 = W2[k*128 + (c-256)]; v2 = W6[k*128 + (c-256)]; }
        else              { v1 = W3[k*64 + (c-384)];  v2 = W7[k*64 + (c-384)]; }
        wht1[c*64 + k] = (_Float16)v1;
        wht2[c*64 + k] = (_Float16)v2;
        if (k == 0) {
            float b1, b2;
            if (c < 128)      { b1 = B0[c];     b2 = B4[c]; }
            else if (c < 256) { b1 = B1[c-128]; b2 = B5[c-128]; }
            else if (c < 384) { b1 = B2[c-256]; b2 = B6[c-256]; }
            else              { b1 = B3[c-384]; b2 = B7[c-384]; }
            ball1[c] = b1;
            ball2[c] = b2;
        }
    }
    for (int i = tid; i < n; i += nt) counts[i] = 0;
    if (tid < 256) state[tid] = 0ull;
}

// ---------------------------------------------------------------------------
// CSR build
// ---------------------------------------------------------------------------
__global__ __launch_bounds__(256) void hist_kernel(const int* __restrict__ dst,
                                                   int* __restrict__ counts, int e) {
    int i = blockIdx.x * 256 + threadIdx.x;
    if (i < e) atomicAdd(&counts[dst[i]], 1);
}

// Decoupled-lookback exclusive scan over counts -> offsets, cursor.
// state[b]: hi32 = status (0 none, 1 aggregate, 2 prefix), lo32 = value.
// Deterministic: all published values are exact partial sums of fixed inputs;
// stale same-value entries from a previous replay are harmless; state is
// zeroed by prep_w_both earlier in the stream each call.
__global__ __launch_bounds__(256) void scan_lookback(
    const int* __restrict__ counts, unsigned long long* __restrict__ state,
    int* __restrict__ offsets, int* __restrict__ cursor, int n, int total) {
    const int b = blockIdx.x, t = threadIdx.x;
    const int idx = b * 256 + t;
    int v = (idx < n) ? counts[idx] : 0;
    __shared__ int s[256];
    __shared__ int exs;
    s[t] = v;
    __syncthreads();
    for (int off = 1; off < 256; off <<= 1) {
        int u = (t >= off) ? s[t - off] : 0;
        __syncthreads();
        s[t] += u;
        __syncthreads();
    }
    const int incl = s[t];
    const int aggregate = s[255];
    if (t == 0) {
        if (b == 0) {
            __hip_atomic_store(&state[0],
                (2ull << 32) | (unsigned)aggregate,
                __ATOMIC_RELEASE, __HIP_MEMORY_SCOPE_AGENT);
            exs = 0;
        } else {
            __hip_atomic_store(&state[b],
                (1ull << 32) | (unsigned)aggregate,
                __ATOMIC_RELEASE, __HIP_MEMORY_SCOPE_AGENT);
            int ex = 0;
            int p = b - 1;
            while (p >= 0) {
                unsigned long long st = __hip_atomic_load(&state[p],
                    __ATOMIC_ACQUIRE, __HIP_MEMORY_SCOPE_AGENT);
                unsigned tag = (unsigned)(st >> 32);
                if (tag == 2u) { ex += (int)(unsigned)st; break; }
                if (tag == 1u) { ex += (int)(unsigned)st; --p; }
                // tag==0: predecessor not published yet -> spin
            }
            __hip_atomic_store(&state[b],
                (2ull << 32) | (unsigned)(ex + aggregate),
                __ATOMIC_RELEASE, __HIP_MEMORY_SCOPE_AGENT);
            exs = ex;
        }
    }
    __syncthreads();
    const int ex = exs;
    if (idx < n) {
        int e0 = ex + incl - v;
        offsets[idx] = e0;
        cursor[idx]  = e0;
    }
    if (idx == 0) offsets[n] = total;
}

__global__ __launch_bounds__(256) void scatter_kernel(const int* __restrict__ src,
                                                      const int* __restrict__ dst,
                                                      int* __restrict__ cursor,
                                                      int* __restrict__ ssrc, int e) {
    int i = blockIdx.x * 256 + threadIdx.x;
    if (i < e) {
        int pos = atomicAdd(&cursor[dst[i]], 1);
        ssrc[pos] = src[i];
    }
}

// ---------------------------------------------------------------------------
// MFMA GEMM (operand-swapped), 64 rows/wave (4 row-tiles amortize each
// weight fragment 4x): [rows,64] @ WhT^T -> Q f16, KV f16, skip f32.
// mfma(A=w_frag, B=x_frag): D row = w-col (4*kg+reg), D col = x-row (li)
// => lane owns 4 consecutive out-cols of one node row -> packed 8B stores.
// ---------------------------------------------------------------------------
template <int F32IN>
__global__ __launch_bounds__(256) void gemm_mfma(
    const void* __restrict__ Xin, int rows,
    const _Float16* __restrict__ WhT,   // [448][64]
    const float* __restrict__ Ball,     // [448]
    _Float16* __restrict__ Qo,          // [N][128]
    _Float16* __restrict__ KVo,         // [N][256] = [K:128 | V:128]
    float* __restrict__ So) {           // [N][64]
    const int lane = threadIdx.x & 63;
    const int w    = threadIdx.x >> 6;
    const int kg   = lane >> 4;
    const int li   = lane & 15;
    const int rbase = blockIdx.x * 256 + w * 64;   // 64 rows per wave

    half8 a0[4], a1[4];
    int rowr[4];
#pragma unroll
    for (int rt = 0; rt < 4; ++rt) {
        int row = rbase + rt * 16 + li;
        rowr[rt] = row;
        int crow = row < rows ? row : rows - 1;
        if constexpr (F32IN) {
            const float* xp = (const float*)Xin + (size_t)crow * 64 + kg * 8;
            float4 f0 = *(const float4*)xp;
            float4 f1 = *(const float4*)(xp + 4);
            float4 f2 = *(const float4*)(xp + 32);
            float4 f3 = *(const float4*)(xp + 36);
            a0[rt] = half8{(_Float16)f0.x, (_Float16)f0.y, (_Float16)f0.z, (_Float16)f0.w,
                           (_Float16)f1.x, (_Float16)f1.y, (_Float16)f1.z, (_Float16)f1.w};
            a1[rt] = half8{(_Float16)f2.x, (_Float16)f2.y, (_Float16)f2.z, (_Float16)f2.w,
                           (_Float16)f3.x, (_Float16)f3.y, (_Float16)f3.z, (_Float16)f3.w};
        } else {
            const _Float16* xp = (const _Float16*)Xin + (size_t)crow * 64 + kg * 8;
            a0[rt] = *(const half8*)xp;
            a1[rt] = *(const half8*)(xp + 32);
        }
    }

#pragma unroll
    for (int t = 0; t < 28; ++t) {
        const _Float16* wp = WhT + (size_t)(t * 16 + li) * 64 + kg * 8;
        half8 b0 = *(const half8*)wp;
        half8 b1 = *(const half8*)(wp + 32);
        const int c0 = t * 16 + kg * 4;
        float4 bias = *(const float4*)(Ball + c0);
#pragma unroll
        for (int rt = 0; rt < 4; ++rt) {
            floatx4 acc = {0.f, 0.f, 0.f, 0.f};
            acc = __builtin_amdgcn_mfma_f32_16x16x32_f16(b0, a0[rt], acc, 0, 0, 0);
            acc = __builtin_amdgcn_mfma_f32_16x16x32_f16(b1, a1[rt], acc, 0, 0, 0);
            const int row = rowr[rt];
            if (row < rows) {
                float o0 = acc[0] + bias.x, o1 = acc[1] + bias.y;
                float o2 = acc[2] + bias.z, o3 = acc[3] + bias.w;
                if (t < 8) {
                    *(half4*)(Qo + (size_t)row * 128 + c0) =
                        half4{(_Float16)o0, (_Float16)o1, (_Float16)o2, (_Float16)o3};
                } else if (t < 24) {
                    *(half4*)(KVo + (size_t)row * 256 + (c0 - 128)) =
                        half4{(_Float16)o0, (_Float16)o1, (_Float16)o2, (_Float16)o3};
                } else {
                    *(float4*)(So + (size_t)row * 64 + (c0 - 384)) =
                        make_float4(o0, o1, o2, o3);
                }
            }
        }
    }
}

// ---------------------------------------------------------------------------
// Attention: 1 wave/node. lane = slot(2b) | head(1b) | li(3b): 8 ch/lane,
// 4 edge-slots, 2 edges/slot/iter (8 edges/iter). Software-pipelined.
// (r8-proven: mem-throughput-bound at ~57 us; VALU diet & deeper pipelining
// both measured null, so body is unchanged.)
// ---------------------------------------------------------------------------
template <int HALF_OUT>
__global__ __launch_bounds__(256) void attn_kernel(
    const _Float16* __restrict__ Qh,    // [N][128] f16
    const _Float16* __restrict__ KV,    // [N][256] f16
    const int* __restrict__ offs, const int* __restrict__ ssrc,
    const float* __restrict__ skip,     // [N][64] f32
    float* __restrict__ outF, _Float16* __restrict__ outH, int n) {
    int node = (blockIdx.x * 256 + threadIdx.x) >> 6;
    int lane = threadIdx.x & 63;
    if (node >= n) return;
    const int slot = lane >> 4;
    const int koff = ((lane >> 3) & 1) * 64 + (lane & 7) * 8;  // head*64 + li*8

    H8 q = *(const H8*)(Qh + (size_t)node * 128 + koff);

    const int beg = offs[node], end = offs[node + 1];
    float m = -INFINITY, l = 0.f;
    __half2 hz = __float2half2_rn(0.f);
    __half2 ha = hz, hb = hz, hc = hz, hd = hz;   // packed O accumulator (8 ch)

    int i = beg;
    bool b0 = false, b1 = false;
    H8 k0, k1, v0, v1;
    if (i < end) {
        int e0 = i + slot, e1 = i + 4 + slot;
        b0 = e0 < end; b1 = e1 < end;
        int s0 = ssrc[b0 ? e0 : end - 1];
        int s1 = ssrc[b1 ? e1 : end - 1];
        const _Float16* p0 = KV + (size_t)s0 * 256 + koff;
        const _Float16* p1 = KV + (size_t)s1 * 256 + koff;
        k0 = *(const H8*)p0; v0 = *(const H8*)(p0 + 128);
        k1 = *(const H8*)p1; v1 = *(const H8*)(p1 + 128);
    }

    while (i < end) {
        const int inext = i + 8;
        bool nb0 = false, nb1 = false;
        H8 nk0, nk1, nv0, nv1;
        if (inext < end) {   // prefetch next iteration (wave-uniform branch)
            int e0 = inext + slot, e1 = inext + 4 + slot;
            nb0 = e0 < end; nb1 = e1 < end;
            int s0 = ssrc[nb0 ? e0 : end - 1];
            int s1 = ssrc[nb1 ? e1 : end - 1];
            const _Float16* p0 = KV + (size_t)s0 * 256 + koff;
            const _Float16* p1 = KV + (size_t)s1 * 256 + koff;
            nk0 = *(const H8*)p0; nv0 = *(const H8*)(p0 + 128);
            nk1 = *(const H8*)p1; nv1 = *(const H8*)(p1 + 128);
        }

        __half2 dh0 = __hfma2(q.a, k0.a, __hfma2(q.b, k0.b, __hfma2(q.c, k0.c, __hmul2(q.d, k0.d))));
        __half2 dh1 = __hfma2(q.a, k1.a, __hfma2(q.b, k1.b, __hfma2(q.c, k1.c, __hmul2(q.d, k1.d))));
        __half2 pd = __halves2half2(__hadd(dh0.x, dh0.y), __hadd(dh1.x, dh1.y));
        pd = __hadd2(pd, shfl_xor_h2(pd, 1));
        pd = __hadd2(pd, shfl_xor_h2(pd, 2));
        pd = __hadd2(pd, shfl_xor_h2(pd, 4));
        float d0 = b0 ? __half2float(pd.x) * 0.125f : -INFINITY;
        float d1 = b1 ? __half2float(pd.y) * 0.125f : -INFINITY;

        float mx = fmaxf(fmaxf(d0, d1), m);
        float sc = (m == -INFINITY) ? 0.f : __expf(m - mx);
        float p0e = b0 ? __expf(d0 - mx) : 0.f;
        float p1e = b1 ? __expf(d1 - mx) : 0.f;
        l = fmaf(l, sc, p0e + p1e);

        __half2 hsc = __float2half2_rn(sc);
        __half2 hp0 = __float2half2_rn(p0e);
        __half2 hp1 = __float2half2_rn(p1e);
        ha = __hfma2(hp0, v0.a, __hfma2(hp1, v1.a, __hmul2(ha, hsc)));
        hb = __hfma2(hp0, v0.b, __hfma2(hp1, v1.b, __hmul2(hb, hsc)));
        hc = __hfma2(hp0, v0.c, __hfma2(hp1, v1.c, __hmul2(hc, hsc)));
        hd = __hfma2(hp0, v0.d, __hfma2(hp1, v1.d, __hmul2(hd, hsc)));
        m = mx;

        i = inext;
        b0 = nb0; b1 = nb1;
        k0 = nk0; k1 = nk1; v0 = nv0; v1 = nv1;
    }

    // unpack accumulator to f32 for the slot merges
    float acc[8];
    {
        float2 t0 = __half22float2(ha), t1 = __half22float2(hb);
        float2 t2 = __half22float2(hc), t3 = __half22float2(hd);
        acc[0] = t0.x; acc[1] = t0.y; acc[2] = t1.x; acc[3] = t1.y;
        acc[4] = t2.x; acc[5] = t2.y; acc[6] = t3.x; acc[7] = t3.y;
    }

    // merge the 4 slot states (xor 16, xor 32)
#pragma unroll
    for (int off = 16; off <= 32; off <<= 1) {
        float mo = __shfl_xor(m, off);
        float lo = __shfl_xor(l, off);
        float ao[8];
#pragma unroll
        for (int j = 0; j < 8; ++j) ao[j] = __shfl_xor(acc[j], off);
        float mm = fmaxf(m, mo);
        float sa = (m  == -INFINITY) ? 0.f : __expf(m  - mm);
        float sb = (mo == -INFINITY) ? 0.f : __expf(mo - mm);
        l = l * sa + lo * sb;
#pragma unroll
        for (int j = 0; j < 8; ++j) acc[j] = acc[j] * sa + ao[j] * sb;
        m = mm;
    }
    // per-head normalize, then head mean (xor 8)
    float inv = 1.f / (l + 1e-16f);
    float r[8];
#pragma unroll
    for (int j = 0; j < 8; ++j) r[j] = acc[j] * inv;
#pragma unroll
    for (int j = 0; j < 8; ++j) r[j] = 0.5f * (r[j] + __shfl_xor(r[j], 8));

    if (lane < 8) {  // slot0, head0: lane owns ch lane*8..+7
        const float4* sp = (const float4*)(skip + (size_t)node * 64 + lane * 8);
        float4 s0 = sp[0], s1 = sp[1];
        float o[8] = {s0.x + r[0], s0.y + r[1], s0.z + r[2], s0.w + r[3],
                      s1.x + r[4], s1.y + r[5], s1.z + r[6], s1.w + r[7]};
        if (HALF_OUT) {
            F16x8 h;
#pragma unroll
            for (int j = 0; j < 8; ++j) h.v[j] = (_Float16)o[j];
            *(F16x8*)(outH + (size_t)node * 64 + lane * 8) = h;
        } else {
            float4* op = (float4*)(outF + (size_t)node * 64 + lane * 8);
            op[0] = make_float4(o[0], o[1], o[2], o[3]);
            op[1] = make_float4(o[4], o[5], o[6], o[7]);
        }
    }
}

// ---------------------------------------------------------------------------
// Host launch: 8 dispatches
// (prep, hist, scan_lookback, scatter, gemm1, attn1, gemm2, attn2)
// ---------------------------------------------------------------------------
extern "C" void kernel_launch(void* const* d_in, const int* in_sizes, int n_in,
                              void* d_out, int out_size, void* d_ws, size_t ws_size,
                              hipStream_t stream) {
    const float* x  = (const float*)d_in[0];
    const int*   ei = (const int*)d_in[1];  // [2,E]: row0=src, row1=dst
    const int N = in_sizes[0] / 64;
    const int E = in_sizes[1] / 2;

    const float* w[16];
    for (int i = 0; i < 16; ++i) w[i] = (const float*)d_in[2 + i];

    char* base = (char*)d_ws;
    size_t off = 0;
    auto alloc = [&](size_t bytes) {
        void* p = base + off;
        off = (off + bytes + 255) & ~(size_t)255;
        return p;
    };
    _Float16* qh   = (_Float16*)alloc((size_t)N * 128 * 2);
    _Float16* kv   = (_Float16*)alloc((size_t)N * 256 * 2);
    float*    sk1  = (float*)alloc((size_t)N * 64 * 4);
    _Float16* h1h  = (_Float16*)alloc((size_t)N * 64 * 2);
    _Float16* wht1 = (_Float16*)alloc(448 * 64 * 2);
    _Float16* wht2 = (_Float16*)alloc(448 * 64 * 2);
    float*    ball1 = (float*)alloc(448 * 4);
    float*    ball2 = (float*)alloc(448 * 4);
    int* counts    = (int*)alloc((size_t)N * 4);
    int* offsets   = (int*)alloc((size_t)(N + 1) * 4);
    int* cursor    = (int*)alloc((size_t)N * 4);
    int* ssrc      = (int*)alloc((size_t)E * 4);
    unsigned long long* state = (unsigned long long*)alloc(256 * 8);

    // --- weight prep + zero counts + zero scan state ---
    prep_w_both<<<224, 256, 0, stream>>>(
        w[0], w[1], w[2], w[3], w[4], w[5], w[6], w[7],
        w[8], w[9], w[10], w[11], w[12], w[13], w[14], w[15],
        wht1, wht2, ball1, ball2, counts, state, N);

    // --- CSR build (graph shared by both layers) ---
    int eb = (E + 255) / 256;
    int nb = (N + 255) / 256;   // 196 blocks (all co-resident: lookback safe)
    hist_kernel<<<eb, 256, 0, stream>>>(ei + E, counts, E);
    scan_lookback<<<nb, 256, 0, stream>>>(counts, state, offsets, cursor, N, E);
    scatter_kernel<<<eb, 256, 0, stream>>>(ei, ei + E, cursor, ssrc, E);

    const int gb = (N + 255) / 256;   // 64 rows/wave, 256 rows/block
    const int ab = (N * 64 + 255) / 256;

    // --- layer 1 (fused fp32->f16 cast of X) ---
    gemm_mfma<1><<<gb, 256, 0, stream>>>(x, N, wht1, ball1, qh, kv, sk1);
    attn_kernel<1><<<ab, 256, 0, stream>>>(qh, kv, offsets, ssrc, sk1,
                                           nullptr, h1h, N);
    // --- layer 2 ---
    gemm_mfma<0><<<gb, 256, 0, stream>>>(h1h, N, wht2, ball2, qh, kv, (float*)d_out);
    attn_kernel<0><<<ab, 256, 0, stream>>>(qh, kv, offsets, ssrc, (float*)d_out,
                                           (float*)d_out, nullptr, N);
}

// Round 12
// 278.328 us; speedup vs baseline: 3.0984x; 1.1340x over previous
//
#include <hip/hip_runtime.h>
#include <hip/hip_fp16.h>
#include <math.h>

// N=50000 nodes, E=800000 edges, D=64, H=2 heads, C=64 per-head, H*C=128
// GEMM output cols concatenated: [Q:128 | K:128 | V:128 | skip:64] = 448

typedef _Float16 half8 __attribute__((ext_vector_type(8)));
typedef _Float16 half4 __attribute__((ext_vector_type(4)));
typedef float floatx4 __attribute__((ext_vector_type(4)));

struct __align__(16) H8 { __half2 a, b, c, d; };   // 8 f16 = 16 B
struct __align__(16) F16x8 { _Float16 v[8]; };     // 16 B

static __device__ inline __half2 shfl_xor_h2(__half2 v, int off) {
    union { __half2 h; int i; } u;
    u.h = v;
    u.i = __shfl_xor(u.i, off);
    return u.h;
}

// ---------------------------------------------------------------------------
// Weight prep (both layers) + zero counts + zero alloc counter
// ---------------------------------------------------------------------------
__global__ __launch_bounds__(256) void prep_w_both(
    const float* __restrict__ W0, const float* __restrict__ B0,
    const float* __restrict__ W1, const float* __restrict__ B1,
    const float* __restrict__ W2, const float* __restrict__ B2,
    const float* __restrict__ W3, const float* __restrict__ B3,
    const float* __restrict__ W4, const float* __restrict__ B4,
    const float* __restrict__ W5, const float* __restrict__ B5,
    const float* __restrict__ W6, const float* __restrict__ B6,
    const float* __restrict__ W7, const float* __restrict__ B7,
    _Float16* __restrict__ wht1, _Float16* __restrict__ wht2,
    float* __restrict__ ball1, float* __restrict__ ball2,
    int* __restrict__ counts, int* __restrict__ gcounter, int n) {
    const int tid = blockIdx.x * 256 + threadIdx.x;
    const int nt  = gridDim.x * 256;
    for (int idx = tid; idx < 448 * 64; idx += nt) {
        int c = idx >> 6, k = idx & 63;
        float v1, v2;
        if (c < 128)      { v1 = W0[k*128 + c];       v2 = W4[k*128 + c]; }
        else if (c < 256) { v1 = W1[k*128 + (c-128)]; v2 = W5[k*128 + (c-128)]; }
        else if (c < 384) { v1 = W2[k*128 + (c-256)]; v2 = W6[k*128 + (c-256)]; }
        else              { v1 = W3[k*64 + (c-384)];  v2 = W7[k*64 + (c-384)]; }
        wht1[c*64 + k] = (_Float16)v1;
        wht2[c*64 + k] = (_Float16)v2;
        if (k == 0) {
            float b1, b2;
            if (c < 128)      { b1 = B0[c];     b2 = B4[c]; }
            else if (c < 256) { b1 = B1[c-128]; b2 = B5[c-128]; }
            else if (c < 384) { b1 = B2[c-256]; b2 = B6[c-256]; }
            else              { b1 = B3[c-384]; b2 = B7[c-384]; }
            ball1[c] = b1;
            ball2[c] = b2;
        }
    }
    for (int i = tid; i < n; i += nt) counts[i] = 0;
    if (tid == 0) *gcounter = 0;
}

// ---------------------------------------------------------------------------
// Shared GEMM tile body (operand-swapped MFMA, 16 rows/wave — r8-proven):
// mfma(A=w_frag, B=x_frag): D row = w-col (4*kg+reg), D col = x-row (li)
// => lane owns 4 consecutive out-cols of one node row -> packed 8B stores.
// ---------------------------------------------------------------------------
template <int F32IN>
static __device__ __forceinline__ void gemm_tile_body(
    const void* __restrict__ Xin, int rows,
    const _Float16* __restrict__ WhT, const float* __restrict__ Ball,
    _Float16* __restrict__ Qo, _Float16* __restrict__ KVo,
    float* __restrict__ So, int blk, int tix) {
    const int lane = tix & 63;
    const int w    = tix >> 6;
    const int kg   = lane >> 4;
    const int li   = lane & 15;
    const int rbase = blk * 64 + w * 16;
    const int row  = rbase + li;
    const int crow = row < rows ? row : rows - 1;

    half8 a0, a1;
    if constexpr (F32IN) {
        const float* xp = (const float*)Xin + (size_t)crow * 64 + kg * 8;
        float4 f0 = *(const float4*)xp;
        float4 f1 = *(const float4*)(xp + 4);
        float4 f2 = *(const float4*)(xp + 32);
        float4 f3 = *(const float4*)(xp + 36);
        a0 = half8{(_Float16)f0.x, (_Float16)f0.y, (_Float16)f0.z, (_Float16)f0.w,
                   (_Float16)f1.x, (_Float16)f1.y, (_Float16)f1.z, (_Float16)f1.w};
        a1 = half8{(_Float16)f2.x, (_Float16)f2.y, (_Float16)f2.z, (_Float16)f2.w,
                   (_Float16)f3.x, (_Float16)f3.y, (_Float16)f3.z, (_Float16)f3.w};
    } else {
        const _Float16* xp = (const _Float16*)Xin + (size_t)crow * 64 + kg * 8;
        a0 = *(const half8*)xp;
        a1 = *(const half8*)(xp + 32);
    }

#pragma unroll
    for (int t = 0; t < 28; ++t) {
        const _Float16* wp = WhT + (size_t)(t * 16 + li) * 64 + kg * 8;
        half8 b0 = *(const half8*)wp;
        half8 b1 = *(const half8*)(wp + 32);
        floatx4 acc = {0.f, 0.f, 0.f, 0.f};
        acc = __builtin_amdgcn_mfma_f32_16x16x32_f16(b0, a0, acc, 0, 0, 0);
        acc = __builtin_amdgcn_mfma_f32_16x16x32_f16(b1, a1, acc, 0, 0, 0);
        const int c0 = t * 16 + kg * 4;
        float4 bias = *(const float4*)(Ball + c0);
        if (row < rows) {
            float o0 = acc[0] + bias.x, o1 = acc[1] + bias.y;
            float o2 = acc[2] + bias.z, o3 = acc[3] + bias.w;
            if (t < 8) {
                *(half4*)(Qo + (size_t)row * 128 + c0) =
                    half4{(_Float16)o0, (_Float16)o1, (_Float16)o2, (_Float16)o3};
            } else if (t < 24) {
                *(half4*)(KVo + (size_t)row * 256 + (c0 - 128)) =
                    half4{(_Float16)o0, (_Float16)o1, (_Float16)o2, (_Float16)o3};
            } else {
                *(float4*)(So + (size_t)row * 64 + (c0 - 384)) =
                    make_float4(o0, o1, o2, o3);
            }
        }
    }
}

// ---------------------------------------------------------------------------
// Fused: GEMM layer 1 (blocks [0,gb)) + dst histogram (blocks [gb,gb+eb)).
// Both depend only on prep; independent of each other.
// ---------------------------------------------------------------------------
__global__ __launch_bounds__(256) void gemm1_hist(
    const float* __restrict__ X, int rows,
    const _Float16* __restrict__ WhT, const float* __restrict__ Ball,
    _Float16* __restrict__ Qo, _Float16* __restrict__ KVo,
    float* __restrict__ So,
    const int* __restrict__ dst, int* __restrict__ counts, int e, int gb) {
    if ((int)blockIdx.x < gb) {
        gemm_tile_body<1>(X, rows, WhT, Ball, Qo, KVo, So,
                          blockIdx.x, threadIdx.x);
    } else {
        int i = ((int)blockIdx.x - gb) * 256 + threadIdx.x;
        if (i < e) atomicAdd(&counts[dst[i]], 1);
    }
}

// ---------------------------------------------------------------------------
// Range allocation (replaces the 3-kernel scan): wave-level prefix sum of
// counts + ONE atomicAdd per wave grabs a contiguous range per node.
// Offsets are disjoint (not monotonic in node id) — attn uses beg+count.
// ---------------------------------------------------------------------------
__global__ __launch_bounds__(256) void alloc_kernel(
    const int* __restrict__ counts, int* __restrict__ gcounter,
    int* __restrict__ offsets, int* __restrict__ cursor, int n) {
    int idx = blockIdx.x * 256 + threadIdx.x;
    int lane = threadIdx.x & 63;
    int v = (idx < n) ? counts[idx] : 0;
    int pre = v;  // inclusive wave prefix
#pragma unroll
    for (int off = 1; off < 64; off <<= 1) {
        int u = __shfl_up(pre, off);
        if (lane >= off) pre += u;
    }
    int wtot = __shfl(pre, 63);
    int base = 0;
    if (lane == 63) base = atomicAdd(gcounter, wtot);
    base = __shfl(base, 63);
    if (idx < n) {
        int ex = base + pre - v;
        offsets[idx] = ex;
        cursor[idx]  = ex;
    }
}

__global__ __launch_bounds__(256) void scatter_kernel(const int* __restrict__ src,
                                                      const int* __restrict__ dst,
                                                      int* __restrict__ cursor,
                                                      int* __restrict__ ssrc, int e) {
    int i = blockIdx.x * 256 + threadIdx.x;
    if (i < e) {
        int pos = atomicAdd(&cursor[dst[i]], 1);
        ssrc[pos] = src[i];
    }
}

// ---------------------------------------------------------------------------
// Standalone GEMM kernel (layer 2)
// ---------------------------------------------------------------------------
template <int F32IN>
__global__ __launch_bounds__(256) void gemm_mfma(
    const void* __restrict__ Xin, int rows,
    const _Float16* __restrict__ WhT, const float* __restrict__ Ball,
    _Float16* __restrict__ Qo, _Float16* __restrict__ KVo,
    float* __restrict__ So) {
    gemm_tile_body<F32IN>(Xin, rows, WhT, Ball, Qo, KVo, So,
                          blockIdx.x, threadIdx.x);
}

// ---------------------------------------------------------------------------
// Attention: 1 wave/node. lane = slot(2b) | head(1b) | li(3b): 8 ch/lane,
// 4 edge-slots, 2 edges/slot/iter (8 edges/iter). Software-pipelined.
// (r8-proven mem-throughput-bound body; now end = beg + counts[node].)
// ---------------------------------------------------------------------------
template <int HALF_OUT>
__global__ __launch_bounds__(256) void attn_kernel(
    const _Float16* __restrict__ Qh,    // [N][128] f16
    const _Float16* __restrict__ KV,    // [N][256] f16
    const int* __restrict__ offs, const int* __restrict__ cnts,
    const int* __restrict__ ssrc,
    const float* __restrict__ skip,     // [N][64] f32
    float* __restrict__ outF, _Float16* __restrict__ outH, int n) {
    int node = (blockIdx.x * 256 + threadIdx.x) >> 6;
    int lane = threadIdx.x & 63;
    if (node >= n) return;
    const int slot = lane >> 4;
    const int koff = ((lane >> 3) & 1) * 64 + (lane & 7) * 8;  // head*64 + li*8

    H8 q = *(const H8*)(Qh + (size_t)node * 128 + koff);

    const int beg = offs[node];
    const int end = beg + cnts[node];
    float m = -INFINITY, l = 0.f;
    __half2 hz = __float2half2_rn(0.f);
    __half2 ha = hz, hb = hz, hc = hz, hd = hz;   // packed O accumulator (8 ch)

    int i = beg;
    bool b0 = false, b1 = false;
    H8 k0, k1, v0, v1;
    if (i < end) {
        int e0 = i + slot, e1 = i + 4 + slot;
        b0 = e0 < end; b1 = e1 < end;
        int s0 = ssrc[b0 ? e0 : end - 1];
        int s1 = ssrc[b1 ? e1 : end - 1];
        const _Float16* p0 = KV + (size_t)s0 * 256 + koff;
        const _Float16* p1 = KV + (size_t)s1 * 256 + koff;
        k0 = *(const H8*)p0; v0 = *(const H8*)(p0 + 128);
        k1 = *(const H8*)p1; v1 = *(const H8*)(p1 + 128);
    }

    while (i < end) {
        const int inext = i + 8;
        bool nb0 = false, nb1 = false;
        H8 nk0, nk1, nv0, nv1;
        if (inext < end) {   // prefetch next iteration (wave-uniform branch)
            int e0 = inext + slot, e1 = inext + 4 + slot;
            nb0 = e0 < end; nb1 = e1 < end;
            int s0 = ssrc[nb0 ? e0 : end - 1];
            int s1 = ssrc[nb1 ? e1 : end - 1];
            const _Float16* p0 = KV + (size_t)s0 * 256 + koff;
            const _Float16* p1 = KV + (size_t)s1 * 256 + koff;
            nk0 = *(const H8*)p0; nv0 = *(const H8*)(p0 + 128);
            nk1 = *(const H8*)p1; nv1 = *(const H8*)(p1 + 128);
        }

        __half2 dh0 = __hfma2(q.a, k0.a, __hfma2(q.b, k0.b, __hfma2(q.c, k0.c, __hmul2(q.d, k0.d))));
        __half2 dh1 = __hfma2(q.a, k1.a, __hfma2(q.b, k1.b, __hfma2(q.c, k1.c, __hmul2(q.d, k1.d))));
        __half2 pd = __halves2half2(__hadd(dh0.x, dh0.y), __hadd(dh1.x, dh1.y));
        pd = __hadd2(pd, shfl_xor_h2(pd, 1));
        pd = __hadd2(pd, shfl_xor_h2(pd, 2));
        pd = __hadd2(pd, shfl_xor_h2(pd, 4));
        float d0 = b0 ? __half2float(pd.x) * 0.125f : -INFINITY;
        float d1 = b1 ? __half2float(pd.y) * 0.125f : -INFINITY;

        float mx = fmaxf(fmaxf(d0, d1), m);
        float sc = (m == -INFINITY) ? 0.f : __expf(m - mx);
        float p0e = b0 ? __expf(d0 - mx) : 0.f;
        float p1e = b1 ? __expf(d1 - mx) : 0.f;
        l = fmaf(l, sc, p0e + p1e);

        __half2 hsc = __float2half2_rn(sc);
        __half2 hp0 = __float2half2_rn(p0e);
        __half2 hp1 = __float2half2_rn(p1e);
        ha = __hfma2(hp0, v0.a, __hfma2(hp1, v1.a, __hmul2(ha, hsc)));
        hb = __hfma2(hp0, v0.b, __hfma2(hp1, v1.b, __hmul2(hb, hsc)));
        hc = __hfma2(hp0, v0.c, __hfma2(hp1, v1.c, __hmul2(hc, hsc)));
        hd = __hfma2(hp0, v0.d, __hfma2(hp1, v1.d, __hmul2(hd, hsc)));
        m = mx;

        i = inext;
        b0 = nb0; b1 = nb1;
        k0 = nk0; k1 = nk1; v0 = nv0; v1 = nv1;
    }

    // unpack accumulator to f32 for the slot merges
    float acc[8];
    {
        float2 t0 = __half22float2(ha), t1 = __half22float2(hb);
        float2 t2 = __half22float2(hc), t3 = __half22float2(hd);
        acc[0] = t0.x; acc[1] = t0.y; acc[2] = t1.x; acc[3] = t1.y;
        acc[4] = t2.x; acc[5] = t2.y; acc[6] = t3.x; acc[7] = t3.y;
    }

    // merge the 4 slot states (xor 16, xor 32)
#pragma unroll
    for (int off = 16; off <= 32; off <<= 1) {
        float mo = __shfl_xor(m, off);
        float lo = __shfl_xor(l, off);
        float ao[8];
#pragma unroll
        for (int j = 0; j < 8; ++j) ao[j] = __shfl_xor(acc[j], off);
        float mm = fmaxf(m, mo);
        float sa = (m  == -INFINITY) ? 0.f : __expf(m  - mm);
        float sb = (mo == -INFINITY) ? 0.f : __expf(mo - mm);
        l = l * sa + lo * sb;
#pragma unroll
        for (int j = 0; j < 8; ++j) acc[j] = acc[j] * sa + ao[j] * sb;
        m = mm;
    }
    // per-head normalize, then head mean (xor 8)
    float inv = 1.f / (l + 1e-16f);
    float r[8];
#pragma unroll
    for (int j = 0; j < 8; ++j) r[j] = acc[j] * inv;
#pragma unroll
    for (int j = 0; j < 8; ++j) r[j] = 0.5f * (r[j] + __shfl_xor(r[j], 8));

    if (lane < 8) {  // slot0, head0: lane owns ch lane*8..+7
        const float4* sp = (const float4*)(skip + (size_t)node * 64 + lane * 8);
        float4 s0 = sp[0], s1 = sp[1];
        float o[8] = {s0.x + r[0], s0.y + r[1], s0.z + r[2], s0.w + r[3],
                      s1.x + r[4], s1.y + r[5], s1.z + r[6], s1.w + r[7]};
        if (HALF_OUT) {
            F16x8 h;
#pragma unroll
            for (int j = 0; j < 8; ++j) h.v[j] = (_Float16)o[j];
            *(F16x8*)(outH + (size_t)node * 64 + lane * 8) = h;
        } else {
            float4* op = (float4*)(outF + (size_t)node * 64 + lane * 8);
            op[0] = make_float4(o[0], o[1], o[2], o[3]);
            op[1] = make_float4(o[4], o[5], o[6], o[7]);
        }
    }
}

// ---------------------------------------------------------------------------
// Host launch: 7 dispatches
// (prep, gemm1+hist, alloc, scatter, attn1, gemm2, attn2)
// ---------------------------------------------------------------------------
extern "C" void kernel_launch(void* const* d_in, const int* in_sizes, int n_in,
                              void* d_out, int out_size, void* d_ws, size_t ws_size,
                              hipStream_t stream) {
    const float* x  = (const float*)d_in[0];
    const int*   ei = (const int*)d_in[1];  // [2,E]: row0=src, row1=dst
    const int N = in_sizes[0] / 64;
    const int E = in_sizes[1] / 2;

    const float* w[16];
    for (int i = 0; i < 16; ++i) w[i] = (const float*)d_in[2 + i];

    char* base = (char*)d_ws;
    size_t off = 0;
    auto alloc = [&](size_t bytes) {
        void* p = base + off;
        off = (off + bytes + 255) & ~(size_t)255;
        return p;
    };
    _Float16* qh   = (_Float16*)alloc((size_t)N * 128 * 2);
    _Float16* kv   = (_Float16*)alloc((size_t)N * 256 * 2);
    float*    sk1  = (float*)alloc((size_t)N * 64 * 4);
    _Float16* h1h  = (_Float16*)alloc((size_t)N * 64 * 2);
    _Float16* wht1 = (_Float16*)alloc(448 * 64 * 2);
    _Float16* wht2 = (_Float16*)alloc(448 * 64 * 2);
    float*    ball1 = (float*)alloc(448 * 4);
    float*    ball2 = (float*)alloc(448 * 4);
    int* counts    = (int*)alloc((size_t)N * 4);
    int* offsets   = (int*)alloc((size_t)(N + 1) * 4);
    int* cursor    = (int*)alloc((size_t)N * 4);
    int* ssrc      = (int*)alloc((size_t)E * 4);
    int* gcounter  = (int*)alloc(256 * 4);

    // --- weight prep + zero counts + zero alloc counter ---
    prep_w_both<<<224, 256, 0, stream>>>(
        w[0], w[1], w[2], w[3], w[4], w[5], w[6], w[7],
        w[8], w[9], w[10], w[11], w[12], w[13], w[14], w[15],
        wht1, wht2, ball1, ball2, counts, gcounter, N);

    const int eb = (E + 255) / 256;   // 3125
    const int nb = (N + 255) / 256;   // 196
    const int gb = (N + 63) / 64;     // 782
    const int ab = (N * 64 + 255) / 256;

    // --- fused: GEMM layer 1 + dst histogram ---
    gemm1_hist<<<gb + eb, 256, 0, stream>>>(x, N, wht1, ball1, qh, kv, sk1,
                                            ei + E, counts, E, gb);
    // --- CSR ranges + scatter ---
    alloc_kernel<<<nb, 256, 0, stream>>>(counts, gcounter, offsets, cursor, N);
    scatter_kernel<<<eb, 256, 0, stream>>>(ei, ei + E, cursor, ssrc, E);

    // --- layer 1 attention ---
    attn_kernel<1><<<ab, 256, 0, stream>>>(qh, kv, offsets, counts, ssrc, sk1,
                                           nullptr, h1h, N);
    // --- layer 2 ---
    gemm_mfma<0><<<gb, 256, 0, stream>>>(h1h, N, wht2, ball2, qh, kv, (float*)d_out);
    attn_kernel<0><<<ab, 256, 0, stream>>>(qh, kv, offsets, counts, ssrc, (float*)d_out,
                                           (float*)d_out, nullptr, N);
}

// Round 13
// 267.237 us; speedup vs baseline: 3.2269x; 1.0415x over previous
//
#include <hip/hip_runtime.h>
#include <hip/hip_fp16.h>
#include <math.h>

// N=50000 nodes, E=800000 edges, D=64, H=2 heads, C=64 per-head, H*C=128
// GEMM output cols concatenated: [Q:128 | K:128 | V:128 | skip:64] = 448

typedef _Float16 half8 __attribute__((ext_vector_type(8)));
typedef _Float16 half4 __attribute__((ext_vector_type(4)));
typedef float floatx4 __attribute__((ext_vector_type(4)));

struct __align__(16) H8 { __half2 a, b, c, d; };   // 8 f16 = 16 B
struct __align__(16) F16x8 { _Float16 v[8]; };     // 16 B

static __device__ inline __half2 shfl_xor_h2(__half2 v, int off) {
    union { __half2 h; int i; } u;
    u.h = v;
    u.i = __shfl_xor(u.i, off);
    return u.h;
}

// ---------------------------------------------------------------------------
// Weight prep (both layers) + zero counts + zero alloc counter
// ---------------------------------------------------------------------------
__global__ __launch_bounds__(256) void prep_w_both(
    const float* __restrict__ W0, const float* __restrict__ B0,
    const float* __restrict__ W1, const float* __restrict__ B1,
    const float* __restrict__ W2, const float* __restrict__ B2,
    const float* __restrict__ W3, const float* __restrict__ B3,
    const float* __restrict__ W4, const float* __restrict__ B4,
    const float* __restrict__ W5, const float* __restrict__ B5,
    const float* __restrict__ W6, const float* __restrict__ B6,
    const float* __restrict__ W7, const float* __restrict__ B7,
    _Float16* __restrict__ wht1, _Float16* __restrict__ wht2,
    float* __restrict__ ball1, float* __restrict__ ball2,
    int* __restrict__ counts, int* __restrict__ gcounter, int n) {
    const int tid = blockIdx.x * 256 + threadIdx.x;
    const int nt  = gridDim.x * 256;
    for (int idx = tid; idx < 448 * 64; idx += nt) {
        int c = idx >> 6, k = idx & 63;
        float v1, v2;
        if (c < 128)      { v1 = W0[k*128 + c];       v2 = W4[k*128 + c]; }
        else if (c < 256) { v1 = W1[k*128 + (c-128)]; v2 = W5[k*128 + (c-128)]; }
        else if (c < 384) { v1 = W2[k*128 + (c-256)]; v2 = W6[k*128 + (c-256)]; }
        else              { v1 = W3[k*64 + (c-384)];  v2 = W7[k*64 + (c-384)]; }
        wht1[c*64 + k] = (_Float16)v1;
        wht2[c*64 + k] = (_Float16)v2;
        if (k == 0) {
            float b1, b2;
            if (c < 128)      { b1 = B0[c];     b2 = B4[c]; }
            else if (c < 256) { b1 = B1[c-128]; b2 = B5[c-128]; }
            else if (c < 384) { b1 = B2[c-256]; b2 = B6[c-256]; }
            else              { b1 = B3[c-384]; b2 = B7[c-384]; }
            ball1[c] = b1;
            ball2[c] = b2;
        }
    }
    for (int i = tid; i < n; i += nt) counts[i] = 0;
    if (tid == 0) *gcounter = 0;
}

// ---------------------------------------------------------------------------
// Shared GEMM tile body (operand-swapped MFMA, 16 rows/wave).
// Col-tiles processed in groups of 4: all 8 weight-fragment loads + 4 bias
// loads issue BEFORE any MFMA consumes them (r12 profile: VGPR=20, VALUBusy
// 3% -> serial load->mfma chain, latency-bound; this raises MLP 2 -> ~12).
// mfma(A=w_frag, B=x_frag): D row = w-col (4*kg+reg), D col = x-row (li)
// => lane owns 4 consecutive out-cols of one node row -> packed 8B stores.
// ---------------------------------------------------------------------------
template <int F32IN>
static __device__ __forceinline__ void gemm_tile_body(
    const void* __restrict__ Xin, int rows,
    const _Float16* __restrict__ WhT, const float* __restrict__ Ball,
    _Float16* __restrict__ Qo, _Float16* __restrict__ KVo,
    float* __restrict__ So, int blk, int tix) {
    const int lane = tix & 63;
    const int w    = tix >> 6;
    const int kg   = lane >> 4;
    const int li   = lane & 15;
    const int rbase = blk * 64 + w * 16;
    const int row  = rbase + li;
    const int crow = row < rows ? row : rows - 1;

    half8 a0, a1;
    if constexpr (F32IN) {
        const float* xp = (const float*)Xin + (size_t)crow * 64 + kg * 8;
        float4 f0 = *(const float4*)xp;
        float4 f1 = *(const float4*)(xp + 4);
        float4 f2 = *(const float4*)(xp + 32);
        float4 f3 = *(const float4*)(xp + 36);
        a0 = half8{(_Float16)f0.x, (_Float16)f0.y, (_Float16)f0.z, (_Float16)f0.w,
                   (_Float16)f1.x, (_Float16)f1.y, (_Float16)f1.z, (_Float16)f1.w};
        a1 = half8{(_Float16)f2.x, (_Float16)f2.y, (_Float16)f2.z, (_Float16)f2.w,
                   (_Float16)f3.x, (_Float16)f3.y, (_Float16)f3.z, (_Float16)f3.w};
    } else {
        const _Float16* xp = (const _Float16*)Xin + (size_t)crow * 64 + kg * 8;
        a0 = *(const half8*)xp;
        a1 = *(const half8*)(xp + 32);
    }

#pragma unroll
    for (int tg = 0; tg < 28; tg += 4) {
        // ---- issue ALL loads for this 4-tile group first ----
        half8 b0[4], b1[4];
        float4 bias[4];
#pragma unroll
        for (int j = 0; j < 4; ++j) {
            const _Float16* wp = WhT + (size_t)((tg + j) * 16 + li) * 64 + kg * 8;
            b0[j] = *(const half8*)wp;
            b1[j] = *(const half8*)(wp + 32);
            bias[j] = *(const float4*)(Ball + (tg + j) * 16 + kg * 4);
        }
        // ---- then compute + store ----
#pragma unroll
        for (int j = 0; j < 4; ++j) {
            const int t = tg + j;
            floatx4 acc = {0.f, 0.f, 0.f, 0.f};
            acc = __builtin_amdgcn_mfma_f32_16x16x32_f16(b0[j], a0, acc, 0, 0, 0);
            acc = __builtin_amdgcn_mfma_f32_16x16x32_f16(b1[j], a1, acc, 0, 0, 0);
            const int c0 = t * 16 + kg * 4;
            if (row < rows) {
                float o0 = acc[0] + bias[j].x, o1 = acc[1] + bias[j].y;
                float o2 = acc[2] + bias[j].z, o3 = acc[3] + bias[j].w;
                if (t < 8) {
                    *(half4*)(Qo + (size_t)row * 128 + c0) =
                        half4{(_Float16)o0, (_Float16)o1, (_Float16)o2, (_Float16)o3};
                } else if (t < 24) {
                    *(half4*)(KVo + (size_t)row * 256 + (c0 - 128)) =
                        half4{(_Float16)o0, (_Float16)o1, (_Float16)o2, (_Float16)o3};
                } else {
                    *(float4*)(So + (size_t)row * 64 + (c0 - 384)) =
                        make_float4(o0, o1, o2, o3);
                }
            }
        }
    }
}

// ---------------------------------------------------------------------------
// Fused: GEMM layer 1 (blocks [0,gb)) + dst histogram (blocks [gb,gb+eb)).
// ---------------------------------------------------------------------------
__global__ __launch_bounds__(256) void gemm1_hist(
    const float* __restrict__ X, int rows,
    const _Float16* __restrict__ WhT, const float* __restrict__ Ball,
    _Float16* __restrict__ Qo, _Float16* __restrict__ KVo,
    float* __restrict__ So,
    const int* __restrict__ dst, int* __restrict__ counts, int e, int gb) {
    if ((int)blockIdx.x < gb) {
        gemm_tile_body<1>(X, rows, WhT, Ball, Qo, KVo, So,
                          blockIdx.x, threadIdx.x);
    } else {
        int i = ((int)blockIdx.x - gb) * 256 + threadIdx.x;
        if (i < e) atomicAdd(&counts[dst[i]], 1);
    }
}

// ---------------------------------------------------------------------------
// Range allocation: wave prefix + ONE atomicAdd per wave -> disjoint ranges.
// ---------------------------------------------------------------------------
__global__ __launch_bounds__(256) void alloc_kernel(
    const int* __restrict__ counts, int* __restrict__ gcounter,
    int* __restrict__ offsets, int* __restrict__ cursor, int n) {
    int idx = blockIdx.x * 256 + threadIdx.x;
    int lane = threadIdx.x & 63;
    int v = (idx < n) ? counts[idx] : 0;
    int pre = v;  // inclusive wave prefix
#pragma unroll
    for (int off = 1; off < 64; off <<= 1) {
        int u = __shfl_up(pre, off);
        if (lane >= off) pre += u;
    }
    int wtot = __shfl(pre, 63);
    int base = 0;
    if (lane == 63) base = atomicAdd(gcounter, wtot);
    base = __shfl(base, 63);
    if (idx < n) {
        int ex = base + pre - v;
        offsets[idx] = ex;
        cursor[idx]  = ex;
    }
}

__global__ __launch_bounds__(256) void scatter_kernel(const int* __restrict__ src,
                                                      const int* __restrict__ dst,
                                                      int* __restrict__ cursor,
                                                      int* __restrict__ ssrc, int e) {
    int i = blockIdx.x * 256 + threadIdx.x;
    if (i < e) {
        int pos = atomicAdd(&cursor[dst[i]], 1);
        ssrc[pos] = src[i];
    }
}

// ---------------------------------------------------------------------------
// Standalone GEMM kernel (layer 2)
// ---------------------------------------------------------------------------
template <int F32IN>
__global__ __launch_bounds__(256) void gemm_mfma(
    const void* __restrict__ Xin, int rows,
    const _Float16* __restrict__ WhT, const float* __restrict__ Ball,
    _Float16* __restrict__ Qo, _Float16* __restrict__ KVo,
    float* __restrict__ So) {
    gemm_tile_body<F32IN>(Xin, rows, WhT, Ball, Qo, KVo, So,
                          blockIdx.x, threadIdx.x);
}

// ---------------------------------------------------------------------------
// Attention: 1 wave/node. lane = slot(2b) | head(1b) | li(3b): 8 ch/lane,
// 4 edge-slots, 2 edges/slot/iter (8 edges/iter). Software-pipelined.
// (r8-proven mem-throughput-bound body; end = beg + counts[node].)
// ---------------------------------------------------------------------------
template <int HALF_OUT>
__global__ __launch_bounds__(256) void attn_kernel(
    const _Float16* __restrict__ Qh,    // [N][128] f16
    const _Float16* __restrict__ KV,    // [N][256] f16
    const int* __restrict__ offs, const int* __restrict__ cnts,
    const int* __restrict__ ssrc,
    const float* __restrict__ skip,     // [N][64] f32
    float* __restrict__ outF, _Float16* __restrict__ outH, int n) {
    int node = (blockIdx.x * 256 + threadIdx.x) >> 6;
    int lane = threadIdx.x & 63;
    if (node >= n) return;
    const int slot = lane >> 4;
    const int koff = ((lane >> 3) & 1) * 64 + (lane & 7) * 8;  // head*64 + li*8

    H8 q = *(const H8*)(Qh + (size_t)node * 128 + koff);

    const int beg = offs[node];
    const int end = beg + cnts[node];
    float m = -INFINITY, l = 0.f;
    __half2 hz = __float2half2_rn(0.f);
    __half2 ha = hz, hb = hz, hc = hz, hd = hz;   // packed O accumulator (8 ch)

    int i = beg;
    bool b0 = false, b1 = false;
    H8 k0, k1, v0, v1;
    if (i < end) {
        int e0 = i + slot, e1 = i + 4 + slot;
        b0 = e0 < end; b1 = e1 < end;
        int s0 = ssrc[b0 ? e0 : end - 1];
        int s1 = ssrc[b1 ? e1 : end - 1];
        const _Float16* p0 = KV + (size_t)s0 * 256 + koff;
        const _Float16* p1 = KV + (size_t)s1 * 256 + koff;
        k0 = *(const H8*)p0; v0 = *(const H8*)(p0 + 128);
        k1 = *(const H8*)p1; v1 = *(const H8*)(p1 + 128);
    }

    while (i < end) {
        const int inext = i + 8;
        bool nb0 = false, nb1 = false;
        H8 nk0, nk1, nv0, nv1;
        if (inext < end) {   // prefetch next iteration (wave-uniform branch)
            int e0 = inext + slot, e1 = inext + 4 + slot;
            nb0 = e0 < end; nb1 = e1 < end;
            int s0 = ssrc[nb0 ? e0 : end - 1];
            int s1 = ssrc[nb1 ? e1 : end - 1];
            const _Float16* p0 = KV + (size_t)s0 * 256 + koff;
            const _Float16* p1 = KV + (size_t)s1 * 256 + koff;
            nk0 = *(const H8*)p0; nv0 = *(const H8*)(p0 + 128);
            nk1 = *(const H8*)p1; nv1 = *(const H8*)(p1 + 128);
        }

        __half2 dh0 = __hfma2(q.a, k0.a, __hfma2(q.b, k0.b, __hfma2(q.c, k0.c, __hmul2(q.d, k0.d))));
        __half2 dh1 = __hfma2(q.a, k1.a, __hfma2(q.b, k1.b, __hfma2(q.c, k1.c, __hmul2(q.d, k1.d))));
        __half2 pd = __halves2half2(__hadd(dh0.x, dh0.y), __hadd(dh1.x, dh1.y));
        pd = __hadd2(pd, shfl_xor_h2(pd, 1));
        pd = __hadd2(pd, shfl_xor_h2(pd, 2));
        pd = __hadd2(pd, shfl_xor_h2(pd, 4));
        float d0 = b0 ? __half2float(pd.x) * 0.125f : -INFINITY;
        float d1 = b1 ? __half2float(pd.y) * 0.125f : -INFINITY;

        float mx = fmaxf(fmaxf(d0, d1), m);
        float sc = (m == -INFINITY) ? 0.f : __expf(m - mx);
        float p0e = b0 ? __expf(d0 - mx) : 0.f;
        float p1e = b1 ? __expf(d1 - mx) : 0.f;
        l = fmaf(l, sc, p0e + p1e);

        __half2 hsc = __float2half2_rn(sc);
        __half2 hp0 = __float2half2_rn(p0e);
        __half2 hp1 = __float2half2_rn(p1e);
        ha = __hfma2(hp0, v0.a, __hfma2(hp1, v1.a, __hmul2(ha, hsc)));
        hb = __hfma2(hp0, v0.b, __hfma2(hp1, v1.b, __hmul2(hb, hsc)));
        hc = __hfma2(hp0, v0.c, __hfma2(hp1, v1.c, __hmul2(hc, hsc)));
        hd = __hfma2(hp0, v0.d, __hfma2(hp1, v1.d, __hmul2(hd, hsc)));
        m = mx;

        i = inext;
        b0 = nb0; b1 = nb1;
        k0 = nk0; k1 = nk1; v0 = nv0; v1 = nv1;
    }

    // unpack accumulator to f32 for the slot merges
    float acc[8];
    {
        float2 t0 = __half22float2(ha), t1 = __half22float2(hb);
        float2 t2 = __half22float2(hc), t3 = __half22float2(hd);
        acc[0] = t0.x; acc[1] = t0.y; acc[2] = t1.x; acc[3] = t1.y;
        acc[4] = t2.x; acc[5] = t2.y; acc[6] = t3.x; acc[7] = t3.y;
    }

    // merge the 4 slot states (xor 16, xor 32)
#pragma unroll
    for (int off = 16; off <= 32; off <<= 1) {
        float mo = __shfl_xor(m, off);
        float lo = __shfl_xor(l, off);
        float ao[8];
#pragma unroll
        for (int j = 0; j < 8; ++j) ao[j] = __shfl_xor(acc[j], off);
        float mm = fmaxf(m, mo);
        float sa = (m  == -INFINITY) ? 0.f : __expf(m  - mm);
        float sb = (mo == -INFINITY) ? 0.f : __expf(mo - mm);
        l = l * sa + lo * sb;
#pragma unroll
        for (int j = 0; j < 8; ++j) acc[j] = acc[j] * sa + ao[j] * sb;
        m = mm;
    }
    // per-head normalize, then head mean (xor 8)
    float inv = 1.f / (l + 1e-16f);
    float r[8];
#pragma unroll
    for (int j = 0; j < 8; ++j) r[j] = acc[j] * inv;
#pragma unroll
    for (int j = 0; j < 8; ++j) r[j] = 0.5f * (r[j] + __shfl_xor(r[j], 8));

    if (lane < 8) {  // slot0, head0: lane owns ch lane*8..+7
        const float4* sp = (const float4*)(skip + (size_t)node * 64 + lane * 8);
        float4 s0 = sp[0], s1 = sp[1];
        float o[8] = {s0.x + r[0], s0.y + r[1], s0.z + r[2], s0.w + r[3],
                      s1.x + r[4], s1.y + r[5], s1.z + r[6], s1.w + r[7]};
        if (HALF_OUT) {
            F16x8 h;
#pragma unroll
            for (int j = 0; j < 8; ++j) h.v[j] = (_Float16)o[j];
            *(F16x8*)(outH + (size_t)node * 64 + lane * 8) = h;
        } else {
            float4* op = (float4*)(outF + (size_t)node * 64 + lane * 8);
            op[0] = make_float4(o[0], o[1], o[2], o[3]);
            op[1] = make_float4(o[4], o[5], o[6], o[7]);
        }
    }
}

// ---------------------------------------------------------------------------
// Host launch: 7 dispatches
// (prep, gemm1+hist, alloc, scatter, attn1, gemm2, attn2)
// ---------------------------------------------------------------------------
extern "C" void kernel_launch(void* const* d_in, const int* in_sizes, int n_in,
                              void* d_out, int out_size, void* d_ws, size_t ws_size,
                              hipStream_t stream) {
    const float* x  = (const float*)d_in[0];
    const int*   ei = (const int*)d_in[1];  // [2,E]: row0=src, row1=dst
    const int N = in_sizes[0] / 64;
    const int E = in_sizes[1] / 2;

    const float* w[16];
    for (int i = 0; i < 16; ++i) w[i] = (const float*)d_in[2 + i];

    char* base = (char*)d_ws;
    size_t off = 0;
    auto alloc = [&](size_t bytes) {
        void* p = base + off;
        off = (off + bytes + 255) & ~(size_t)255;
        return p;
    };
    _Float16* qh   = (_Float16*)alloc((size_t)N * 128 * 2);
    _Float16* kv   = (_Float16*)alloc((size_t)N * 256 * 2);
    float*    sk1  = (float*)alloc((size_t)N * 64 * 4);
    _Float16* h1h  = (_Float16*)alloc((size_t)N * 64 * 2);
    _Float16* wht1 = (_Float16*)alloc(448 * 64 * 2);
    _Float16* wht2 = (_Float16*)alloc(448 * 64 * 2);
    float*    ball1 = (float*)alloc(448 * 4);
    float*    ball2 = (float*)alloc(448 * 4);
    int* counts    = (int*)alloc((size_t)N * 4);
    int* offsets   = (int*)alloc((size_t)(N + 1) * 4);
    int* cursor    = (int*)alloc((size_t)N * 4);
    int* ssrc      = (int*)alloc((size_t)E * 4);
    int* gcounter  = (int*)alloc(256 * 4);

    // --- weight prep + zero counts + zero alloc counter ---
    prep_w_both<<<224, 256, 0, stream>>>(
        w[0], w[1], w[2], w[3], w[4], w[5], w[6], w[7],
        w[8], w[9], w[10], w[11], w[12], w[13], w[14], w[15],
        wht1, wht2, ball1, ball2, counts, gcounter, N);

    const int eb = (E + 255) / 256;   // 3125
    const int nb = (N + 255) / 256;   // 196
    const int gb = (N + 63) / 64;     // 782
    const int ab = (N * 64 + 255) / 256;

    // --- fused: GEMM layer 1 + dst histogram ---
    gemm1_hist<<<gb + eb, 256, 0, stream>>>(x, N, wht1, ball1, qh, kv, sk1,
                                            ei + E, counts, E, gb);
    // --- CSR ranges + scatter ---
    alloc_kernel<<<nb, 256, 0, stream>>>(counts, gcounter, offsets, cursor, N);
    scatter_kernel<<<eb, 256, 0, stream>>>(ei, ei + E, cursor, ssrc, E);

    // --- layer 1 attention ---
    attn_kernel<1><<<ab, 256, 0, stream>>>(qh, kv, offsets, counts, ssrc, sk1,
                                           nullptr, h1h, N);
    // --- layer 2 ---
    gemm_mfma<0><<<gb, 256, 0, stream>>>(h1h, N, wht2, ball2, qh, kv, (float*)d_out);
    attn_kernel<0><<<ab, 256, 0, stream>>>(qh, kv, offsets, counts, ssrc, (float*)d_out,
                                           (float*)d_out, nullptr, N);
}